// Round 2
// baseline (547.104 us; speedup 1.0000x reference)
//
#include <hip/hip_runtime.h>
#include <hip/hip_bf16.h>

typedef __attribute__((ext_vector_type(8))) short bf16x8;
typedef __attribute__((ext_vector_type(4))) short bf16x4;
typedef __attribute__((ext_vector_type(4))) float f32x4;

#define MFMA32(a,b,c) __builtin_amdgcn_mfma_f32_16x16x32_bf16(a,b,c,0,0,0)

#if __has_builtin(__builtin_amdgcn_mfma_f32_16x16x16bf16_1k)
#define MFMA16(a,b,c) __builtin_amdgcn_mfma_f32_16x16x16bf16_1k(a,b,c,0,0,0)
#else
static __device__ __forceinline__ f32x4 mfma16_asm(bf16x4 a, bf16x4 b, f32x4 c){
  asm volatile("v_mfma_f32_16x16x16_bf16 %0, %1, %2, %0" : "+v"(c) : "v"(a), "v"(b));
  return c;
}
#define MFMA16(a,b,c) mfma16_asm(a,b,c)
#endif

#define NEGV -65504.0f

__device__ __forceinline__ unsigned short f2bf(float f){
  union { float f; unsigned u; } x; x.f = f;
  unsigned r = x.u + 0x7fffu + ((x.u >> 16) & 1u);
  return (unsigned short)(r >> 16);
}

// ---------------- fp32 -> bf16 convert (x4 vectorized) ----------------
__global__ void cvt_kernel(const float* __restrict__ in, unsigned short* __restrict__ out, int n4){
  int i = blockIdx.x * 256 + threadIdx.x;
  if (i >= n4) return;
  const float4 f = ((const float4*)in)[i];
  ushort4 u;
  u.x = f2bf(f.x); u.y = f2bf(f.y); u.z = f2bf(f.z); u.w = f2bf(f.w);
  ((ushort4*)out)[i] = u;
}

// ---------------- QKV GEMM: X[8192,768] @ W[2304,768]^T + b ----------------
// scatter into q (scaled by 0.125), k, v as [B*H=96, N=1024, D=64] bf16
__global__ __launch_bounds__(256) void gemm_qkv(
    const unsigned short* __restrict__ X,
    const unsigned short* __restrict__ W,
    const float* __restrict__ bias,
    unsigned short* __restrict__ Qd,
    unsigned short* __restrict__ Kd,
    unsigned short* __restrict__ Vd)
{
  const int K = 768;
  int bid = blockIdx.x;
  int bm = bid & 63;        // 64 M-blocks of 128
  int bn = bid >> 6;        // 18 N-blocks of 128
  int wave = threadIdx.x >> 6;
  int lane = threadIdx.x & 63;
  int lo = lane & 15, g = lane >> 4;
  int row0 = bm * 128 + (wave >> 1) * 64;
  int col0 = bn * 128 + (wave & 1) * 64;

  f32x4 acc[4][4] = {};
  for (int k0 = 0; k0 < K; k0 += 32) {
    bf16x8 a[4], b[4];
    int ko = k0 + g * 8;
#pragma unroll
    for (int i = 0; i < 4; ++i)
      a[i] = *(const bf16x8*)(X + (size_t)(row0 + i*16 + lo) * K + ko);
#pragma unroll
    for (int i = 0; i < 4; ++i)
      b[i] = *(const bf16x8*)(W + (size_t)(col0 + i*16 + lo) * K + ko);
#pragma unroll
    for (int mi = 0; mi < 4; ++mi)
#pragma unroll
      for (int ni = 0; ni < 4; ++ni)
        acc[mi][ni] = MFMA32(a[mi], b[ni], acc[mi][ni]);
  }
  // D frag: col = lane&15, row = (lane>>4)*4 + reg   (m89-verified)
#pragma unroll
  for (int ni = 0; ni < 4; ++ni) {
    int col = col0 + ni*16 + lo;
    float bc = bias[col];
    int which = col / 768;           // 0=q 1=k 2=v (uniform over 16-lane group)
    int rem = col - which * 768;
    int h = rem >> 6, d = rem & 63;
    unsigned short* dst = (which == 0) ? Qd : (which == 1) ? Kd : Vd;
    float scale = (which == 0) ? 0.125f : 1.0f;   // fold SCALE into q (exact pow2)
#pragma unroll
    for (int mi = 0; mi < 4; ++mi) {
#pragma unroll
      for (int r = 0; r < 4; ++r) {
        int row = row0 + mi*16 + g*4 + r;
        int bb = row >> 10, n = row & 1023;
        dst[(((size_t)bb*12 + h)*1024 + n)*64 + d] = f2bf((acc[mi][ni][r] + bc) * scale);
      }
    }
  }
}

// ---------------- fused attention core ----------------
// grid (16 qblocks, 96 bh); block 256 = 4 waves; each wave owns 16 q rows.
// Swapped QK^T: S^T frag -> lane owns q-row (lane&15), 4 kpos per lane.
__global__ __launch_bounds__(256) void attn_kernel(
    const unsigned short* __restrict__ Qd,
    const unsigned short* __restrict__ Kd,
    const unsigned short* __restrict__ Vd,
    const float* __restrict__ bias,          // [12,1024,1024] fp32
    const int* __restrict__ mask,            // [8,1024,1024] int32 (bool)
    float* __restrict__ out1,                // [96,1024,1024] fp32
    unsigned short* __restrict__ ctx)        // [8192,768] bf16
{
  const int N = 1024, D = 64;
  int bh = blockIdx.y;
  int b = bh / 12, h = bh - b * 12;
  int wave = threadIdx.x >> 6, lane = threadIdx.x & 63;
  int lo = lane & 15, g = lane >> 4;
  int q0 = blockIdx.x * 64 + wave * 16;
  int qrow = q0 + lo;

  const size_t qoff = ((size_t)bh * N + qrow) * D;
  bf16x8 qf0 = *(const bf16x8*)(Qd + qoff + g*8);        // B-frag: col=q, k=d
  bf16x8 qf1 = *(const bf16x8*)(Qd + qoff + 32 + g*8);

  const float* bias_row = bias + ((size_t)h * N + qrow) * N;
  const int* mask_row = mask + ((size_t)b * N + qrow) * N;
  float* out_row = out1 + ((size_t)bh * N + qrow) * N;

  float m_run = -INFINITY, l_run = 0.0f;
  f32x4 o[4] = {};   // O^T: lane holds q=lo, d = c*16 + g*4 + reg

  for (int kv = 0; kv < N; kv += 16) {
    size_t koff = ((size_t)bh * N + kv + lo) * D;
    bf16x8 kf0 = *(const bf16x8*)(Kd + koff + g*8);      // A-frag: row=kpos, k=d
    bf16x8 kf1 = *(const bf16x8*)(Kd + koff + 32 + g*8);
    f32x4 s = {};
    s = MFMA32(kf0, qf0, s);
    s = MFMA32(kf1, qf1, s);
    // s[r] = S[q=lo][kpos = kv + g*4 + r]

    int mc = kv + g*4;
    int4 mv = *(const int4*)(mask_row + mc);             // 4 int32 bool values
    float4 bi = *(const float4*)(bias_row + mc);
    float sp0 = (mv.x ? NEGV : s[0]) + bi.x;
    float sp1 = (mv.y ? NEGV : s[1]) + bi.y;
    float sp2 = (mv.z ? NEGV : s[2]) + bi.z;
    float sp3 = (mv.w ? NEGV : s[3]) + bi.w;
    float4 ov; ov.x = sp0; ov.y = sp1; ov.z = sp2; ov.w = sp3;
    *(float4*)(out_row + mc) = ov;                       // attn_wo_softmax dump

    // online softmax (row lives in 4 lanes {lo, lo+16, lo+32, lo+48})
    float tmax = fmaxf(fmaxf(sp0, sp1), fmaxf(sp2, sp3));
    tmax = fmaxf(tmax, __shfl_xor(tmax, 16));
    tmax = fmaxf(tmax, __shfl_xor(tmax, 32));
    float mnew = fmaxf(m_run, tmax);
    float alpha = __expf(m_run - mnew);
    float p0 = __expf(sp0 - mnew);
    float p1 = __expf(sp1 - mnew);
    float p2 = __expf(sp2 - mnew);
    float p3 = __expf(sp3 - mnew);
    float ts = (p0 + p1) + (p2 + p3);
    ts += __shfl_xor(ts, 16);
    ts += __shfl_xor(ts, 32);
    l_run = l_run * alpha + ts;
    m_run = mnew;

    bf16x4 pf;   // B-frag of 16x16x16: col=q=lo, k=g*4+e -> exactly our s-layout
    pf[0] = (short)f2bf(p0); pf[1] = (short)f2bf(p1);
    pf[2] = (short)f2bf(p2); pf[3] = (short)f2bf(p3);

#pragma unroll
    for (int c = 0; c < 4; ++c) {
#pragma unroll
      for (int r = 0; r < 4; ++r) o[c][r] *= alpha;
      // A-frag = V^T chunk: row=d=c*16+lo, k=kpos=g*4+e  -> V[kv+g*4+e][c*16+lo]
      size_t vb = ((size_t)bh * N + kv + g*4) * D + c*16 + lo;
      bf16x4 vf;
      vf[0] = (short)Vd[vb];
      vf[1] = (short)Vd[vb + D];
      vf[2] = (short)Vd[vb + 2*D];
      vf[3] = (short)Vd[vb + 3*D];
      o[c] = MFMA16(vf, pf, o[c]);
    }
  }

  float inv = 1.0f / l_run;
  size_t crow = ((size_t)b * N + qrow) * 768 + h * 64;
#pragma unroll
  for (int c = 0; c < 4; ++c) {
    ushort4 u;
    u.x = f2bf(o[c][0] * inv);
    u.y = f2bf(o[c][1] * inv);
    u.z = f2bf(o[c][2] * inv);
    u.w = f2bf(o[c][3] * inv);
    *(ushort4*)(ctx + crow + c*16 + g*4) = u;   // d = c*16 + g*4 + reg, 8B store
  }
}

// ---------------- proj GEMM: ctx[8192,768] @ Wp[768,768]^T + b -> fp32 ----------------
__global__ __launch_bounds__(256) void gemm_proj(
    const unsigned short* __restrict__ X,
    const unsigned short* __restrict__ W,
    const float* __restrict__ bias,
    float* __restrict__ out)
{
  const int K = 768;
  int bid = blockIdx.x;
  int bm = bid & 63;       // 64 M-blocks
  int bn = bid >> 6;       // 6 N-blocks
  int wave = threadIdx.x >> 6;
  int lane = threadIdx.x & 63;
  int lo = lane & 15, g = lane >> 4;
  int row0 = bm * 128 + (wave >> 1) * 64;
  int col0 = bn * 128 + (wave & 1) * 64;

  f32x4 acc[4][4] = {};
  for (int k0 = 0; k0 < K; k0 += 32) {
    bf16x8 a[4], b[4];
    int ko = k0 + g * 8;
#pragma unroll
    for (int i = 0; i < 4; ++i)
      a[i] = *(const bf16x8*)(X + (size_t)(row0 + i*16 + lo) * K + ko);
#pragma unroll
    for (int i = 0; i < 4; ++i)
      b[i] = *(const bf16x8*)(W + (size_t)(col0 + i*16 + lo) * K + ko);
#pragma unroll
    for (int mi = 0; mi < 4; ++mi)
#pragma unroll
      for (int ni = 0; ni < 4; ++ni)
        acc[mi][ni] = MFMA32(a[mi], b[ni], acc[mi][ni]);
  }
#pragma unroll
  for (int ni = 0; ni < 4; ++ni) {
    int col = col0 + ni*16 + lo;
    float bc = bias[col];
#pragma unroll
    for (int mi = 0; mi < 4; ++mi) {
#pragma unroll
      for (int r = 0; r < 4; ++r) {
        int row = row0 + mi*16 + g*4 + r;
        out[(size_t)row * 768 + col] = acc[mi][ni][r] + bc;
      }
    }
  }
}

extern "C" void kernel_launch(void* const* d_in, const int* in_sizes, int n_in,
                              void* d_out, int out_size, void* d_ws, size_t ws_size,
                              hipStream_t stream) {
  const float* x            = (const float*)d_in[0];
  const float* rel_pos_bias = (const float*)d_in[1];
  const int* mask           = (const int*)d_in[2];     // bool -> int32
  const float* Wqkv         = (const float*)d_in[3];
  const float* bqkv         = (const float*)d_in[4];
  const float* Wproj        = (const float*)d_in[5];
  const float* bproj        = (const float*)d_in[6];

  float* out0 = (float*)d_out;                         // [8,1024,768]
  float* out1 = out0 + (size_t)8 * 1024 * 768;         // [8,12,1024,1024]

  // workspace layout (bytes), total ~67.6 MB
  char* ws = (char*)d_ws;
  unsigned short* xb  = (unsigned short*)(ws);                 // 12,582,912
  unsigned short* wqb = (unsigned short*)(ws + 12582912);      //  3,538,944
  unsigned short* wpb = (unsigned short*)(ws + 16121856);      //  1,179,648
  unsigned short* Qb  = (unsigned short*)(ws + 17301504);      // 12,582,912
  unsigned short* Kb  = (unsigned short*)(ws + 29884416);      // 12,582,912
  unsigned short* Vb  = (unsigned short*)(ws + 42467328);      // 12,582,912
  unsigned short* ctx = (unsigned short*)(ws + 55050240);      // 12,582,912

  cvt_kernel<<<6144, 256, 0, stream>>>(x,     xb,  1572864);
  cvt_kernel<<<1728, 256, 0, stream>>>(Wqkv,  wqb,  442368);
  cvt_kernel<<<576,  256, 0, stream>>>(Wproj, wpb,  147456);

  gemm_qkv<<<1152, 256, 0, stream>>>(xb, wqb, bqkv, Qb, Kb, Vb);

  attn_kernel<<<dim3(16, 96), 256, 0, stream>>>(Qb, Kb, Vb, rel_pos_bias, mask,
                                                out1, ctx);

  gemm_proj<<<384, 256, 0, stream>>>(ctx, wpb, bproj, out0);
}